// Round 3
// baseline (287.904 us; speedup 1.0000x reference)
//
#include <hip/hip_runtime.h>
#include <math.h>

// Problem constants
constexpr int B_ = 4, C_ = 256, H4 = 96, W4 = 320, HF = 384, WF = 1280;
constexpr float EPSV = 1e-6f;
constexpr int LOW = B_ * H4 * W4;      // 122880
constexpr int FULL = B_ * HF * WF;     // 1966080

// Phase-1 decomposition: block = (cq, b, y): full 320-px row, 64 channels.
constexpr int CQ  = 4;                 // channel quarters
constexpr int CPB = C_ / CQ;           // 64 channels per block
constexpr int CG  = 2;                 // channels per stage
constexpr int NIT = CPB / CG;          // 32 stages
constexpr int NBUF = 4;                // LDS ring depth (4 needed: see race note)
constexpr int BUF_FLOATS = CG * 2 * W4;    // 1280 floats = 5120 B per buffer

// Async global->LDS DMA, 16 B per lane, LDS dest = wave-uniform base + lane*16.
__device__ __forceinline__ void async_copy16(const float* g, float* l)
{
    __builtin_amdgcn_global_load_lds(
        (const __attribute__((address_space(1))) void*)g,
        (__attribute__((address_space(3))) void*)l,
        16, 0, 0);
}

// Phase 1 main: banded correlation partials over 64 channels of one full row.
// Rationale: previous rounds fetched 256 B per (block,channel,tensor) at 120 KB
// stride -> ~480 concurrent 256 B DRAM streams -> ~29% DRAM efficiency (1.8 TB/s
// invariant across 3 structures). Full-row blocks fetch 1280 B contiguous per
// (channel,tensor). Staging via global_load_lds DMA (no VGPR liveness for the
// compiler to collapse) with counted vmcnt: 2 stages (10 KB/block) in flight
// across raw s_barriers. Thread = pixel x; halo is mod-320 within the row.
__global__ __launch_bounds__(320)
void phase1(const float* __restrict__ fL, const float* __restrict__ fR,
            float* __restrict__ P)
{
    const int bi = blockIdx.x;
    const int cq = bi / (B_ * H4);         // slow: channel quarter
    const int r  = bi % (B_ * H4);         // fast: (b,y) -> adjacent blocks read
    const int b  = r / H4;                 // adjacent rows (DRAM page locality)
    const int y  = r % H4;
    const int tid  = threadIdx.x;          // 0..319
    const int wave = tid >> 6;             // 0..4
    const int x = tid;                     // owned pixel column

    const size_t chanStride = (size_t)H4 * W4;   // 30720
    const int c0 = cq * CPB;

    __shared__ float lds[NBUF * BUF_FLOATS];     // 20 KiB

    // Staging role: thread t DMAs 16 B; buffer float index fi = 4t.
    // Layout [ch][tensor][x]: ch = t/160, tensor = (t/80)&1, xq = 4*(t%80).
    const int sch  = tid / 160;
    const int stns = (tid / 80) & 1;
    const int sxq  = 4 * (tid % 80);
    const float* const sbase = (stns ? fR : fL)
        + ((size_t)b * C_ + (c0 + sch)) * chanStride + (size_t)y * W4 + sxq;
    // per-stage advance: CG * chanStride floats

    // wave-uniform LDS chunk: wave w covers floats [256w, 256w+256) of a buffer
    float* const ldswave = &lds[0] + wave * 256;

    // 7-neighbor indices with circular wrap (jnp.roll)
    int idx[7];
#pragma unroll
    for (int k = 0; k < 7; ++k) {
        int t = x + k - 3;
        if (t < 0) t += W4; else if (t >= W4) t -= W4;
        idx[k] = t;
    }

    float dot[7] = {0.f,0.f,0.f,0.f,0.f,0.f,0.f};
    float ssL = 0.f, ssR = 0.f;

    // Prologue: stages 0,1 in flight.
    async_copy16(sbase,                        ldswave + 0 * BUF_FLOATS);
    async_copy16(sbase + (size_t)CG * chanStride, ldswave + 1 * BUF_FLOATS);

    auto compute = [&](int g) {
        const float* bf = &lds[(g & (NBUF - 1)) * BUF_FLOATS];
#pragma unroll
        for (int ch = 0; ch < CG; ++ch) {
            const float* cf = bf + ch * (2 * W4);
            const float a = cf[x];                 // fL
            const float* wr = cf + W4;             // fR row
            float w[7];
#pragma unroll
            for (int k = 0; k < 7; ++k) w[k] = wr[idx[k]];
#pragma unroll
            for (int k = 0; k < 7; ++k) dot[k] = fmaf(a, w[k], dot[k]);
            ssL = fmaf(a, a, ssL);
            ssR = fmaf(w[3], w[3], ssR);           // w[3] == fR[x]
        }
    };

    // Race note (why NBUF=4): stage(g+2) is issued pre-barrier(g); the previous
    // reader of that buffer is compute(g-2), which finished before barrier(g-1)
    // < issue point. With NBUF=3 the reader compute(g-3+2)=compute(g-1)... the
    // writer would overlap a live reader. 4 buffers give one barrier of slack.
    for (int g = 0; g < NIT - 2; ++g) {            // g = 0..29
        async_copy16(sbase + (size_t)(g + 2) * CG * chanStride,
                     ldswave + ((g + 2) & (NBUF - 1)) * BUF_FLOATS);
        // own stages g+1,g+2 outstanding -> vmcnt(2) confirms stage g landed
        asm volatile("s_waitcnt vmcnt(2)" ::: "memory");
        __builtin_amdgcn_s_barrier();              // all waves' stage-g landed
        asm volatile("" ::: "memory");             // ds_reads can't hoist above
        compute(g);
    }
    // Tail: g = 30 (only stage 31 outstanding), g = 31 (none)
    asm volatile("s_waitcnt vmcnt(1)" ::: "memory");
    __builtin_amdgcn_s_barrier();
    asm volatile("" ::: "memory");
    compute(NIT - 2);
    asm volatile("s_waitcnt vmcnt(0)" ::: "memory");
    __builtin_amdgcn_s_barrier();
    asm volatile("" ::: "memory");
    compute(NIT - 1);

    // Partials: 9 floats/pixel, summed across the 4 cq-blocks by device atomics.
    // Comp-major layout -> coalesced adds. P lives in the out buffer (memset 0).
    const size_t rowoff = ((size_t)b * H4 + y) * W4 + x;
#pragma unroll
    for (int k = 0; k < 7; ++k)
        atomicAdd(&P[(size_t)k * LOW + rowoff], dot[k]);
    atomicAdd(&P[(size_t)7 * LOW + rowoff], ssL);
    atomicAdd(&P[(size_t)8 * LOW + rowoff], ssR);
}

// Phase 1b (fixup): combine partials -> cosine costs -> softmax -> dref, conf.
__global__ __launch_bounds__(320)
void phase1b(const float* __restrict__ P, const float* __restrict__ D,
             float* __restrict__ dref, float* __restrict__ conf)
{
    const int bi = blockIdx.x;                 // b*H4 + y
    const int b = bi / H4, y = bi % H4;
    const int x = threadIdx.x;
    const size_t rowoff = (size_t)bi * W4 + x;

    float dot[7];
#pragma unroll
    for (int k = 0; k < 7; ++k) dot[k] = P[(size_t)k * LOW + rowoff];
    const float ssL = P[(size_t)7 * LOW + rowoff];
    const float ssR = P[(size_t)8 * LOW + rowoff];

    __shared__ float sss[W4];                  // squared fR norms, full row
    sss[x] = ssR;
    __syncthreads();

    const float nL = fmaxf(sqrtf(ssL), EPSV);
    float cost[7];
#pragma unroll
    for (int k = 0; k < 7; ++k) {
        // k indexes neighbor x+(k-3); reference cost[i] (d=i-3) uses x+(3-i)
        int t = x + k - 3;
        if (t < 0) t += W4; else if (t >= W4) t -= W4;
        const float nR = fmaxf(sqrtf(sss[t]), EPSV);
        cost[6 - k] = (dot[k] / (nL * nR)) * 10.0f;   // /TEMP, TEMP=0.1
    }
    float m = cost[0];
#pragma unroll
    for (int i = 1; i < 7; ++i) m = fmaxf(m, cost[i]);
    float sum = 0.f, dsum = 0.f;
#pragma unroll
    for (int i = 0; i < 7; ++i) {
        const float e = __expf(cost[i] - m);
        sum += e;
        dsum += e * (float)(i - 3);
    }
    const float delta = dsum / sum;
    const float cf = 1.0f / sum;               // max p = exp(0)/sum

    // Exact 4x downsample of disp_full: y0=4y+1,y1=4y+2, wy=wx=0.5 -> mean 2x2, /4
    const int Y0 = 4 * y + 1, X0 = 4 * x + 1;
    const size_t dbase = ((size_t)b * HF + Y0) * WF + X0;
    const float s4 = D[dbase] + D[dbase + 1] + D[dbase + WF] + D[dbase + WF + 1];
    const float disp0 = s4 * 0.0625f;          // (sum/4)/4

    dref[rowoff] = disp0 + delta;
    conf[rowoff] = cf;
}

// dq = dref - 0.2 * Laplacian(dref) computed on the fly (zero padding)
__device__ __forceinline__ float dq_val(const float* __restrict__ dref,
                                        size_t base, int yq, int xq)
{
    size_t i = base + (size_t)yq * W4 + xq;
    float c  = dref[i];
    float up = (yq > 0)      ? dref[i - W4] : 0.f;
    float dn = (yq < H4 - 1) ? dref[i + W4] : 0.f;
    float lf = (xq > 0)      ? dref[i - 1]  : 0.f;
    float rt = (xq < W4 - 1) ? dref[i + 1]  : 0.f;
    return c - 0.2f * (up + dn + lf + rt - 4.f * c);
}

// Phase 2: 4x bilinear upsample of dq (*4) and conf; 4 outputs per thread.
__global__ void phase2(const float* __restrict__ dref, const float* __restrict__ cf,
                       float* __restrict__ out)
{
    const int idx = blockIdx.x * blockDim.x + threadIdx.x;
    constexpr int WQ = WF / 4;                 // 320 quads per row
    if (idx >= FULL / 4) return;
    const int k = idx % WQ;
    const int Y = (idx / WQ) % HF;
    const int b = idx / (WQ * HF);

    const float ys = fmaxf((Y + 0.5f) * 0.25f - 0.5f, 0.f);
    const float y0f = floorf(ys);
    const float wy = ys - y0f;
    const int y0 = min((int)y0f, H4 - 1);
    const int y1 = min(y0 + 1, H4 - 1);
    const size_t base = (size_t)b * (H4 * W4);

    const int xa = max(k - 1, 0);
    const int xb = k;
    const int xc = min(k + 1, W4 - 1);

    const float da = (1.f - wy) * dq_val(dref, base, y0, xa) + wy * dq_val(dref, base, y1, xa);
    const float db = (1.f - wy) * dq_val(dref, base, y0, xb) + wy * dq_val(dref, base, y1, xb);
    const float dc = (1.f - wy) * dq_val(dref, base, y0, xc) + wy * dq_val(dref, base, y1, xc);

    const size_t r0 = base + (size_t)y0 * W4;
    const size_t r1 = base + (size_t)y1 * W4;
    const float ca = (1.f - wy) * cf[r0 + xa] + wy * cf[r1 + xa];
    const float cb = (1.f - wy) * cf[r0 + xb] + wy * cf[r1 + xb];
    const float cc = (1.f - wy) * cf[r0 + xc] + wy * cf[r1 + xc];

    float4 dv, cv;
    dv.x = 4.0f * (0.375f * da + 0.625f * db);
    dv.y = 4.0f * (0.125f * da + 0.875f * db);
    dv.z = 4.0f * (0.875f * db + 0.125f * dc);
    dv.w = 4.0f * (0.625f * db + 0.375f * dc);
    cv.x = 0.375f * ca + 0.625f * cb;
    cv.y = 0.125f * ca + 0.875f * cb;
    cv.z = 0.875f * cb + 0.125f * cc;
    cv.w = 0.625f * cb + 0.375f * cc;

    const size_t o = (((size_t)b * HF + Y) * WF) + 4 * k;
    *(float4*)&out[o] = dv;
    *(float4*)&out[(size_t)FULL + o] = cv;
}

extern "C" void kernel_launch(void* const* d_in, const int* in_sizes, int n_in,
                              void* d_out, int out_size, void* d_ws, size_t ws_size,
                              hipStream_t stream)
{
    const float* fL = (const float*)d_in[0];
    const float* fR = (const float*)d_in[1];
    const float* D  = (const float*)d_in[2];
    float* out  = (float*)d_out;
    float* ws   = (float*)d_ws;
    float* dref = ws;
    float* conf = ws + LOW;
    float* P    = out;   // 9*LOW floats = 4.4 MB scratch in out; phase2 overwrites

    hipMemsetAsync(P, 0, (size_t)9 * LOW * sizeof(float), stream);
    phase1<<<CQ * B_ * H4, 320, 0, stream>>>(fL, fR, P);
    phase1b<<<B_ * H4, 320, 0, stream>>>(P, D, dref, conf);
    phase2<<<(FULL / 4 + 255) / 256, 256, 0, stream>>>(dref, conf, out);
}